// Round 4
// baseline (168.273 us; speedup 1.0000x reference)
//
#include <hip/hip_runtime.h>

#define CC 256
#define HH 96
#define WW 128
#define PP 9
#define OFF 4
#define PLANE (HH * WW)      // 12288

#define HB 3                 // output rows per WG
#define RN (HB + 8)          // 11 staged in2 rows
#define PX 32                // output px per WG
#define SW 48                // staged in2 cols (32 + 16 halo)
#define PAD 20               // u32 stride per px (16 c-pairs + 4 pad)
#define KCH 32               // channels per chunk = MFMA K
#define NCHK (CC / KCH)      // 8
#define TPB 384              // 6 waves = 3 rows x 2 px1-blocks
#define DPAD 36              // f32 px1-stride in D scratch
#define NU2 6                // in2 staging units per thread (ceil 2112/384)
#define U2TOT (RN * 16 * 12) // 2112 units: 11 rows x 16 c-pairs x 12 quads
#define ADVB (KCH * PLANE * 4)   // byte advance per chunk
#define PLB (PLANE * 4)          // plane byte stride
#define DSL (HB * SW * DPAD)     // 5184 f32 per dy-slice of D scratch

typedef _Float16 f16x8 __attribute__((ext_vector_type(8)));
typedef float fx4 __attribute__((ext_vector_type(4)));

union U16 { uint4 u; f16x8 h; };

__device__ __forceinline__ unsigned pk(float a, float b) {
#if __has_builtin(__builtin_amdgcn_cvt_pkrtz)
  auto r = __builtin_amdgcn_cvt_pkrtz(a, b);
  unsigned u; __builtin_memcpy(&u, &r, 4); return u;
#else
  _Float16 h0 = (_Float16)a, h1 = (_Float16)b;
  unsigned u = 0, v = 0; __builtin_memcpy(&u, &h0, 2); __builtin_memcpy(&v, &h1, 2);
  return u | (v << 16);
#endif
}

// MFMA formulation (verified round 3): D[px1,px2] = sum_c in1[c,px1]*in2[c,px2];
// out(dy,dx,px1) = D_dy[px1, px1+dx-4].  512 WGs = 2/CU, 6 waves/WG.
// Round-4 changes: staging = float4 quad units (13 dwordx4/thread/chunk vs 52
// dword), all loads for chunk c+1 batched into regs before COMPUTE(c) -> one
// overlapped latency exposure per chunk instead of ~7 serial ones.
__global__ __launch_bounds__(TPB, 3) void corr_kernel(const float* __restrict__ in1,
                                                      const float* __restrict__ in2,
                                                      float* __restrict__ out) {
  __shared__ __align__(16) unsigned s2[RN][SW][PAD];  // 42240 B
  __shared__ __align__(16) unsigned s1[HB][PX][PAD];  //  7680 B -> 49.9 KB

  // XCD swizzle: XCD k owns 4 adjacent 3-row bands -> dy-halo stays in-XCD L2.
  const int bx = blockIdx.x;
  const int xcd = bx & 7;
  const int s = bx >> 3;           // 0..63
  const int xq = s & 3;
  const int t2 = s >> 2;           // 0..15
  const int b = t2 & 3;
  const int band = xcd * 4 + (t2 >> 2);
  const int h0 = band * HB;

  const int tid = threadIdx.x;
  const int wv = tid >> 6;
  const int wr = wv >> 1;          // row 0..2
  const int wp = wv & 1;           // px1-block 0..1
  const int lane = tid & 63;
  const int ln = lane & 15;        // MFMA m/n index
  const int lg = lane >> 4;        // MFMA k-group

  const char* in2p = (const char*)in2;
  const char* in1p = (const char*)in1;

  // ---- in2 staging units: u = tid + 384k; cp=u&15, qx=(u>>4)%12, r=u/192.
  // Quad alignment (OFF=4): every 4-px quad is fully in-bounds or fully OOB.
  unsigned o2[NU2];        // byte offsets (clamped, always safe to load)
  unsigned vmask = 0;      // per-unit validity bits
#pragma unroll
  for (int k = 0; k < NU2; ++k) {
    const int u = tid + TPB * k;
    const bool inr = u < U2TOT;
    const int uu = inr ? u : tid;
    const int cp = uu & 15;
    const int qx = (uu >> 4) % 12;
    const int r = uu / 192;
    const int rg = h0 - OFF + r;
    const int gx = xq * PX - OFF + 4 * qx;
    const bool ok = inr && ((unsigned)rg < HH) && ((unsigned)gx <= WW - 4);
    const int rgc = rg < 0 ? 0 : (rg > HH - 1 ? HH - 1 : rg);
    const int gxc = gx < 0 ? 0 : (gx > WW - 4 ? WW - 4 : gx);
    o2[k] = (unsigned)(((b * CC + 2 * cp) * PLANE + rgc * WW + gxc) * 4);
    vmask |= (ok ? 1u : 0u) << k;
  }
  // ---- in1 staging unit: exactly 1/thread, always in-bounds.
  const int cp1 = tid & 15, qx1 = (tid >> 4) & 7, r1 = tid >> 7;
  unsigned o1 = (unsigned)(((b * CC + 2 * cp1) * PLANE + (h0 + r1) * WW + xq * PX + 4 * qx1) * 4);
  unsigned* const l1 = &s1[r1][4 * qx1][cp1];

  // pre-zero s2: OOB halo slots stay zero forever
  for (int i = tid; i < RN * SW * PAD; i += TPB) ((unsigned*)s2)[i] = 0u;

  fx4 acc[PP][2];
#pragma unroll
  for (int dy = 0; dy < PP; ++dy)
#pragma unroll
    for (int t = 0; t < 2; ++t) acc[dy][t] = (fx4)0.f;

  // prefetch registers: 13 float4 (~56 VGPR), live across COMPUTE + 1 barrier.
  float4 fa[NU2], fb[NU2], ga, gb;

  auto ISSUE = [&]() {
#pragma unroll
    for (int k = 0; k < NU2; ++k) {
      fa[k] = *(const float4*)(in2p + o2[k]);
      fb[k] = *(const float4*)(in2p + o2[k] + PLB);
      o2[k] += ADVB;
    }
    ga = *(const float4*)(in1p + o1);
    gb = *(const float4*)(in1p + o1 + PLB);
    o1 += ADVB;
  };

  auto PKSTORE = [&]() {
#pragma unroll
    for (int k = 0; k < NU2; ++k) {
      if ((vmask >> k) & 1) {
        const int u = tid + TPB * k;
        const int cp = u & 15;
        const int qx = (u >> 4) % 12;
        const int r = u / 192;
        unsigned* base = &s2[r][4 * qx][cp];
        base[0 * PAD] = pk(fa[k].x, fb[k].x);
        base[1 * PAD] = pk(fa[k].y, fb[k].y);
        base[2 * PAD] = pk(fa[k].z, fb[k].z);
        base[3 * PAD] = pk(fa[k].w, fb[k].w);
      }
    }
    l1[0 * PAD] = pk(ga.x, gb.x);
    l1[1 * PAD] = pk(ga.y, gb.y);
    l1[2 * PAD] = pk(ga.z, gb.z);
    l1[3 * PAD] = pk(ga.w, gb.w);
  };

  auto COMPUTE = [&]() {
    U16 a; a.u = *(const uint4*)&s1[wr][wp * 16 + ln][4 * lg];
#pragma unroll
    for (int dy = 0; dy < PP; ++dy) {
#pragma unroll
      for (int t = 0; t < 2; ++t) {
        U16 bb; bb.u = *(const uint4*)&s2[wr + dy][wp * 16 + 16 * t + ln][4 * lg];
        acc[dy][t] = __builtin_amdgcn_mfma_f32_16x16x32_f16(a.h, bb.h, acc[dy][t], 0, 0, 0);
      }
    }
  };

  // ---- prologue
  ISSUE();                             // chunk 0 loads in flight
  __syncthreads();                     // pre-zero visible (also drains chunk-0 loads)
  PKSTORE();
  __syncthreads();                     // buf visible

  // ---- main loop: single LDS buffer, reg-prefetch pipeline
#pragma unroll 1
  for (int c = 0; c < NCHK; ++c) {
    if (c + 1 < NCHK) ISSUE();         // chunk c+1 loads overlap COMPUTE(c)
    __builtin_amdgcn_sched_barrier(0); // keep load issue above compute
    COMPUTE();
    __syncthreads();                   // all readers done (drains prefetch too)
    if (c + 1 < NCHK) {
      PKSTORE();
      __syncthreads();                 // writes visible for next COMPUTE
    }
  }

  // ---- epilogue: 2 dy-slices per LDS pass (10 barriers vs 18).
  // D layout: col(n=px2) = lane&15, row(m=px1) = (lane>>4)*4 + reg.
  float* DL = (float*)&s2[0][0][0];    // 2 x 5184 f32 = 41.5 KB overlay
#pragma unroll
  for (int d0 = 0; d0 < PP; d0 += 2) {
    const int nd = (d0 + 1 < PP) ? 2 : 1;
#pragma unroll
    for (int sl = 0; sl < 2; ++sl) {
      if (sl < nd) {
#pragma unroll
        for (int t = 0; t < 2; ++t) {
          const int p2 = wp * 16 + 16 * t + ln;
          *(fx4*)&DL[sl * DSL + (wr * SW + p2) * DPAD + wp * 16 + 4 * lg] = acc[d0 + sl][t];
        }
      }
    }
    __syncthreads();
    const int tot = nd * HB * PP * PX;   // nd*864
    for (int id = tid; id < tot; id += TPB) {
      int slice = 0, rem = id;
      if (rem >= HB * PP * PX) { slice = 1; rem -= HB * PP * PX; }
      const int px = rem & 31;
      const int v = rem >> 5;            // 0..26
      const int dx = v % PP;
      const int rr = v / PP;
      out[(size_t)((b * PP + d0 + slice) * PP + dx) * PLANE + (size_t)(h0 + rr) * WW + xq * PX + px] =
          DL[slice * DSL + (rr * SW + px + dx) * DPAD + px];
    }
    __syncthreads();
  }
}

extern "C" void kernel_launch(void* const* d_in, const int* in_sizes, int n_in,
                              void* d_out, int out_size, void* d_ws, size_t ws_size,
                              hipStream_t stream) {
  const float* in1 = (const float*)d_in[0];
  const float* in2 = (const float*)d_in[1];
  float* out = (float*)d_out;
  // 512 blocks = 4b * 32 bands * 4 xq (xcd-swizzled) = exactly 2 WG/CU
  corr_kernel<<<dim3(512), dim3(TPB), 0, stream>>>(in1, in2, out);
}

// Round 5
// 168.050 us; speedup vs baseline: 1.0013x; 1.0013x over previous
//
#include <hip/hip_runtime.h>

#define CC 256
#define HH 96
#define WW 128
#define PP 9
#define OFF 4
#define PLANE (HH * WW)      // 12288

#define HB 3                 // output rows per WG
#define RN (HB + 8)          // 11 staged in2 rows
#define PX 32                // output px per WG
#define SW 48                // staged in2 cols (32 + 16 halo)
#define PAD 20               // u32 stride per px (16 c-pairs + 4 pad)
#define KCH 32               // channels per chunk = MFMA K
#define NCHK (CC / KCH)      // 8
#define TPB 384              // 6 waves = 3 rows x 2 px1-blocks
#define DPAD 36              // f32 px1-stride in D scratch
#define DSL (HB * SW * DPAD) // 5184 f32 per dy-slice of D scratch
#define NU2 6                // in2 staging units per thread
#define ADVB (KCH * PLANE * 4)   // byte advance per chunk
#define PLB (PLANE * 4)          // plane byte stride

typedef _Float16 f16x8 __attribute__((ext_vector_type(8)));
typedef float fx4 __attribute__((ext_vector_type(4)));

union U16 { uint4 u; f16x8 h; };

__device__ __forceinline__ unsigned pk(float a, float b) {
#if __has_builtin(__builtin_amdgcn_cvt_pkrtz)
  auto r = __builtin_amdgcn_cvt_pkrtz(a, b);
  unsigned u; __builtin_memcpy(&u, &r, 4); return u;
#else
  _Float16 h0 = (_Float16)a, h1 = (_Float16)b;
  unsigned u = 0, v = 0; __builtin_memcpy(&u, &h0, 2); __builtin_memcpy(&v, &h1, 2);
  return u | (v << 16);
#endif
}

// MFMA formulation (verified round 3): D[px1,px2] = sum_c in1[c,px1]*in2[c,px2];
// out(dy,dx,px1) = D_dy[px1, px1+dx-4].  512 WGs = 2/CU, 6 waves/WG.
// Round 5 = round-3 staging (guarded scalar loads, b128 LDS stores) + batched
// issue: ALL 56 loads of chunk c+1 issued before COMPUTE(c); single vmcnt
// drain per chunk, hidden under compute (round 4 showed 56-reg batch doesn't
// spill: VGPR=84, WRITE_SIZE clean).
__global__ __launch_bounds__(TPB, 3) void corr_kernel(const float* __restrict__ in1,
                                                      const float* __restrict__ in2,
                                                      float* __restrict__ out) {
  __shared__ __align__(16) unsigned s2[RN][SW][PAD];  // 42240 B
  __shared__ __align__(16) unsigned s1[HB][PX][PAD];  //  7680 B -> 49.9 KB

  // XCD swizzle: XCD k owns 4 adjacent 3-row bands -> dy-halo stays in-XCD L2.
  const int bx = blockIdx.x;
  const int xcd = bx & 7;
  const int s = bx >> 3;           // 0..63
  const int xq = s & 3;
  const int t2 = s >> 2;           // 0..15
  const int b = t2 & 3;
  const int band = xcd * 4 + (t2 >> 2);
  const int h0 = band * HB;

  const int tid = threadIdx.x;
  const int wv = tid >> 6;
  const int wr = wv >> 1;          // row 0..2
  const int wp = wv & 1;           // px1-block 0..1
  const int lane = tid & 63;
  const int ln = lane & 15;        // MFMA m/n index
  const int lg = lane >> 4;        // MFMA k-group

  const char* in2p = (const char*)in2;
  const char* in1p = (const char*)in1;

  // ---- in2 staging roles (round-3 mapping): spx 0..47, scb c-block, sr0.
  const int spx = tid % 48;
  const int sq = tid / 48;         // 0..7
  const int scb = sq & 3;          // c-block (8 channels)
  const int sr0 = sq >> 2;         // 0..1; unit k covers row r = sr0 + 2k
  const int gx2 = xq * PX - OFF + spx;
  const bool okx = (unsigned)gx2 < WW;

  unsigned o2[NU2];                // byte offsets (valid units only)
  unsigned vmask = 0;
#pragma unroll
  for (int k = 0; k < NU2; ++k) {
    const int r = sr0 + 2 * k;
    const int rg = h0 - OFF + r;
    const bool ok = (r < RN) && okx && ((unsigned)rg < HH);
    o2[k] = ok ? (unsigned)(((b * CC + scb * 8) * PLANE + rg * WW + gx2) * 4) : 0u;
    vmask |= (ok ? 1u : 0u) << k;
  }
  // ---- in1 staging role (round-3 mapping): 1 unit/thread, always in-bounds.
  const int tpx = tid & 31;
  const int tq = tid >> 5;         // 0..11
  const int tcb = tq & 3;
  const int tr = tq >> 2;          // 0..2
  const unsigned o1 = (unsigned)(((b * CC + tcb * 8) * PLANE + (h0 + tr) * WW + xq * PX + tpx) * 4);

  // pre-zero s2: OOB halo slots stay zero forever (OOB pattern is chunk-invariant)
  for (int i = tid; i < RN * SW * PAD; i += TPB) ((unsigned*)s2)[i] = 0u;

  fx4 acc[PP][2];
#pragma unroll
  for (int dy = 0; dy < PP; ++dy)
#pragma unroll
    for (int t = 0; t < 2; ++t) acc[dy][t] = (fx4)0.f;

  // batched prefetch registers: 56 f32, live across COMPUTE + 1 barrier.
  float f[NU2][8], g[8];

  auto ISSUE = [&](unsigned cadv) {
#pragma unroll
    for (int k = 0; k < NU2; ++k)
      if ((vmask >> k) & 1) {
        const float* p = (const float*)(in2p + (o2[k] + cadv));
#pragma unroll
        for (int i = 0; i < 8; ++i) f[k][i] = p[i * PLANE];
      }
    {
      const float* p = (const float*)(in1p + (o1 + cadv));
#pragma unroll
      for (int i = 0; i < 8; ++i) g[i] = p[i * PLANE];
    }
  };

  auto PKSTORE = [&]() {
#pragma unroll
    for (int k = 0; k < NU2; ++k)
      if ((vmask >> k) & 1) {
        const int r = sr0 + 2 * k;
        uint4 w;
        w.x = pk(f[k][0], f[k][1]); w.y = pk(f[k][2], f[k][3]);
        w.z = pk(f[k][4], f[k][5]); w.w = pk(f[k][6], f[k][7]);
        *(uint4*)&s2[r][spx][4 * scb] = w;   // one b128 store (round-3 pattern)
      }
    {
      uint4 w;
      w.x = pk(g[0], g[1]); w.y = pk(g[2], g[3]);
      w.z = pk(g[4], g[5]); w.w = pk(g[6], g[7]);
      *(uint4*)&s1[tr][tpx][4 * tcb] = w;
    }
  };

  auto COMPUTE = [&]() {
    U16 a; a.u = *(const uint4*)&s1[wr][wp * 16 + ln][4 * lg];
#pragma unroll
    for (int dy = 0; dy < PP; ++dy) {
#pragma unroll
      for (int t = 0; t < 2; ++t) {
        U16 bb; bb.u = *(const uint4*)&s2[wr + dy][wp * 16 + 16 * t + ln][4 * lg];
        acc[dy][t] = __builtin_amdgcn_mfma_f32_16x16x32_f16(a.h, bb.h, acc[dy][t], 0, 0, 0);
      }
    }
  };

  // ---- prologue
  ISSUE(0u);                           // chunk-0 loads in flight
  __syncthreads();                     // pre-zero visible (drains chunk-0 loads too)
  PKSTORE();
  __syncthreads();                     // buf visible

  // ---- main loop: single LDS buffer, one latency exposure per chunk
#pragma unroll 1
  for (int c = 0; c < NCHK; ++c) {
    if (c + 1 < NCHK) ISSUE((unsigned)(c + 1) * ADVB);  // overlap COMPUTE(c)
    __builtin_amdgcn_sched_barrier(0); // pin load issue above compute
    COMPUTE();
    __syncthreads();                   // readers done; drains prefetch (hidden)
    if (c + 1 < NCHK) {
      PKSTORE();
      __syncthreads();                 // writes visible for next COMPUTE
    }
  }

  // ---- epilogue: 2 dy-slices per LDS pass (10 barriers).
  // D layout: col(n=px2) = lane&15, row(m=px1) = (lane>>4)*4 + reg.
  float* DL = (float*)&s2[0][0][0];    // 2 x 5184 f32 = 41.5 KB overlay
#pragma unroll
  for (int d0 = 0; d0 < PP; d0 += 2) {
    const int nd = (d0 + 1 < PP) ? 2 : 1;
#pragma unroll
    for (int sl = 0; sl < 2; ++sl) {
      if (sl < nd) {
#pragma unroll
        for (int t = 0; t < 2; ++t) {
          const int p2 = wp * 16 + 16 * t + ln;
          *(fx4*)&DL[sl * DSL + (wr * SW + p2) * DPAD + wp * 16 + 4 * lg] = acc[d0 + sl][t];
        }
      }
    }
    __syncthreads();
    const int tot = nd * HB * PP * PX;   // nd*864
    for (int id = tid; id < tot; id += TPB) {
      int slice = 0, rem = id;
      if (rem >= HB * PP * PX) { slice = 1; rem -= HB * PP * PX; }
      const int px = rem & 31;
      const int v = rem >> 5;            // 0..26
      const int dx = v % PP;
      const int rr = v / PP;
      out[(size_t)((b * PP + d0 + slice) * PP + dx) * PLANE + (size_t)(h0 + rr) * WW + xq * PX + px] =
          DL[slice * DSL + (rr * SW + px + dx) * DPAD + px];
    }
    __syncthreads();
  }
}

extern "C" void kernel_launch(void* const* d_in, const int* in_sizes, int n_in,
                              void* d_out, int out_size, void* d_ws, size_t ws_size,
                              hipStream_t stream) {
  const float* in1 = (const float*)d_in[0];
  const float* in2 = (const float*)d_in[1];
  float* out = (float*)d_out;
  // 512 blocks = 4b * 32 bands * 4 xq (xcd-swizzled) = exactly 2 WG/CU
  corr_kernel<<<dim3(512), dim3(TPB), 0, stream>>>(in1, in2, out);
}

// Round 6
// 157.805 us; speedup vs baseline: 1.0663x; 1.0649x over previous
//
#include <hip/hip_runtime.h>

#define CC 256
#define HH 96
#define WW 128
#define PP 9
#define OFF 4
#define PLANE (HH * WW)      // 12288

#define HB 3                 // output rows per WG
#define PX 32                // output px per WG
#define SW 48                // staged in2 cols (32 + 16 halo)
#define PAD 20               // u32 stride per px (16 c-pairs + 4 pad)
#define KCH 32               // channels per chunk = MFMA K
#define NCHK (CC / KCH)      // 8
#define TPB 384              // 6 waves = 3 rows x 2 px1-blocks
#define RNMAX 7              // staged in2 rows (dy-half A: 7, B: 6)
#define DPAD 36              // f32 px1-stride in D scratch
#define NU 4                 // in2 staging units per thread
#define ADVB (KCH * PLANE * 4)   // byte advance per chunk

typedef _Float16 f16x8 __attribute__((ext_vector_type(8)));
typedef float fx4 __attribute__((ext_vector_type(4)));

union U16 { uint4 u; f16x8 h; };

__device__ __forceinline__ unsigned pk(float a, float b) {
#if __has_builtin(__builtin_amdgcn_cvt_pkrtz)
  auto r = __builtin_amdgcn_cvt_pkrtz(a, b);
  unsigned u; __builtin_memcpy(&u, &r, 4); return u;
#else
  _Float16 h0 = (_Float16)a, h1 = (_Float16)b;
  unsigned u = 0, v = 0; __builtin_memcpy(&u, &h0, 2); __builtin_memcpy(&v, &h1, 2);
  return u | (v << 16);
#endif
}

// MFMA formulation (validated round 3): D[px1,px2] = sum_c in1[c,px1]*in2[c,px2];
// out(dy,dx,px1) = D_dy[px1, px1+dx-4].
// Round 6: dy-split. Each WG covers dy in {0..4} (half A) or {5..8} (half B)
// -> staged in2 rows 7/6 instead of 11, LDS 34.6 KB instead of 49.9 KB ->
// 3-4 WG/CU instead of 2 (18-24 waves vs 12). Staging keeps round-3's
// interleaved per-unit load->pk->store (the batched variants of rounds 4/5
// regressed 1.5x: burst issue + vmcnt(0)-at-barrier serializes).
__global__ __launch_bounds__(TPB, 5) void corr_kernel(const float* __restrict__ in1,
                                                      const float* __restrict__ in2,
                                                      float* __restrict__ out) {
  __shared__ __align__(16) unsigned s2[RNMAX][SW][PAD];  // 26880 B
  __shared__ __align__(16) unsigned s1[HB][PX][PAD];     //  7680 B -> 34.6 KB

  // 1024 WGs: XCD k owns bands 4k..4k+3; both dy-halves of a band on same XCD
  // (shared in2 rows stay in-XCD L2).
  const int bx = blockIdx.x;
  const int xcd = bx & 7;
  const int s = bx >> 3;           // 0..127
  const int half = s & 1;          // dy-half
  const int xq = (s >> 1) & 3;
  const int b = (s >> 3) & 3;
  const int bl = s >> 5;           // 0..3
  const int band = xcd * 4 + bl;
  const int h0 = band * HB;
  const int d0 = half ? 5 : 0;     // first dy of this WG
  const int ndy = half ? 4 : 5;    // dy count (block-uniform)
  const int rnw = ndy + HB - 1;    // staged rows: 7 (A) / 6 (B)

  const int tid = threadIdx.x;
  const int wv = tid >> 6;
  const int wr = wv >> 1;          // row 0..2
  const int wp = wv & 1;           // px1-block 0..1
  const int lane = tid & 63;
  const int ln = lane & 15;        // MFMA m/n index
  const int lg = lane >> 4;        // MFMA k-group

  const char* in2p = (const char*)in2;
  const char* in1p = (const char*)in1;

  // ---- in2 staging roles (round-3 mapping, rows relative to d0):
  const int spx = tid % 48;
  const int sq = tid / 48;         // 0..7
  const int scb = sq & 3;          // c-block (8 channels)
  const int sr0 = sq >> 2;         // 0..1; unit k covers row r = sr0 + 2k
  const int gx2 = xq * PX - OFF + spx;
  const bool okx = (unsigned)gx2 < WW;

  unsigned o2[NU];                 // byte offsets (valid units only)
  unsigned vmask = 0;
#pragma unroll
  for (int k = 0; k < NU; ++k) {
    const int r = sr0 + 2 * k;                 // slot in s2
    const int rg = h0 - OFF + d0 + r;          // global row
    const bool ok = (r < rnw) && okx && ((unsigned)rg < HH);
    o2[k] = ok ? (unsigned)(((b * CC + scb * 8) * PLANE + rg * WW + gx2) * 4) : 0u;
    vmask |= (ok ? 1u : 0u) << k;
  }
  // ---- in1 staging role: 1 b128-unit/thread, always in-bounds.
  const int tpx = tid & 31;
  const int tq = tid >> 5;         // 0..11
  const int tcb = tq & 3;
  const int tr = tq >> 2;          // 0..2
  const unsigned o1 = (unsigned)(((b * CC + tcb * 8) * PLANE + (h0 + tr) * WW + xq * PX + tpx) * 4);

  // pre-zero s2: OOB halo slots stay zero forever
  for (int i = tid; i < RNMAX * SW * PAD; i += TPB) ((unsigned*)s2)[i] = 0u;

  fx4 acc[5][2];
#pragma unroll
  for (int d = 0; d < 5; ++d)
#pragma unroll
    for (int t = 0; t < 2; ++t) acc[d][t] = (fx4)0.f;

  __syncthreads();                 // pre-zero visible before first staging

  // ---- main loop: round-3 structure, 2 barriers/chunk, interleaved staging
#pragma unroll 1
  for (int c = 0; c < NCHK; ++c) {
    const unsigned cadv = (unsigned)c * ADVB;
    // stage in2: per unit load->pk->b128 store (self-staggering across waves)
#pragma unroll
    for (int k = 0; k < NU; ++k)
      if ((vmask >> k) & 1) {
        const float* p = (const float*)(in2p + (o2[k] + cadv));
        const float l0 = p[0], l1 = p[PLANE], l2 = p[2 * PLANE], l3 = p[3 * PLANE];
        const float l4 = p[4 * PLANE], l5 = p[5 * PLANE], l6 = p[6 * PLANE], l7 = p[7 * PLANE];
        uint4 w;
        w.x = pk(l0, l1); w.y = pk(l2, l3); w.z = pk(l4, l5); w.w = pk(l6, l7);
        *(uint4*)&s2[sr0 + 2 * k][spx][4 * scb] = w;
      }
    // stage in1
    {
      const float* p = (const float*)(in1p + (o1 + cadv));
      const float l0 = p[0], l1 = p[PLANE], l2 = p[2 * PLANE], l3 = p[3 * PLANE];
      const float l4 = p[4 * PLANE], l5 = p[5 * PLANE], l6 = p[6 * PLANE], l7 = p[7 * PLANE];
      uint4 w;
      w.x = pk(l0, l1); w.y = pk(l2, l3); w.z = pk(l4, l5); w.w = pk(l6, l7);
      *(uint4*)&s1[tr][tpx][4 * tcb] = w;
    }
    __syncthreads();

    // compute: A reused across all MFMAs of the chunk; s2 slot r = wr + d
    U16 a; a.u = *(const uint4*)&s1[wr][wp * 16 + ln][4 * lg];
#pragma unroll
    for (int d = 0; d < 5; ++d)
      if (d < ndy) {               // block-uniform guard keeps acc index static
#pragma unroll
        for (int t = 0; t < 2; ++t) {
          U16 bb; bb.u = *(const uint4*)&s2[wr + d][wp * 16 + 16 * t + ln][4 * lg];
          acc[d][t] = __builtin_amdgcn_mfma_f32_16x16x32_f16(a.h, bb.h, acc[d][t], 0, 0, 0);
        }
      }
    __syncthreads();
  }

  // ---- epilogue: 1 dy-slice per pass (round-3 pattern).
  // D layout: col(n=px2) = lane&15, row(m=px1) = (lane>>4)*4 + reg.
  float* DL = (float*)&s2[0][0][0];  // 5184 f32 = 20.7 KB overlay (fits 26.9 KB)
#pragma unroll
  for (int d = 0; d < 5; ++d)
    if (d < ndy) {                   // block-uniform: barriers stay uniform
#pragma unroll
      for (int t = 0; t < 2; ++t) {
        const int p2 = wp * 16 + 16 * t + ln;
        *(fx4*)&DL[(wr * SW + p2) * DPAD + wp * 16 + 4 * lg] = acc[d][t];
      }
      __syncthreads();
#pragma unroll
      for (int k2 = 0; k2 < 3; ++k2) {
        const int id = tid + TPB * k2;
        if (id < HB * PP * PX) {
          const int px = id & 31;
          const int v = id >> 5;       // 0..26
          const int dx = v % PP;
          const int rr = v / PP;
          out[(size_t)((b * PP + d0 + d) * PP + dx) * PLANE + (size_t)(h0 + rr) * WW + xq * PX + px] =
              DL[(rr * SW + px + dx) * DPAD + px];  // px2w = px1 + dx - 4 + 4halo
        }
      }
      __syncthreads();
    }
}

extern "C" void kernel_launch(void* const* d_in, const int* in_sizes, int n_in,
                              void* d_out, int out_size, void* d_ws, size_t ws_size,
                              hipStream_t stream) {
  const float* in1 = (const float*)d_in[0];
  const float* in2 = (const float*)d_in[1];
  float* out = (float*)d_out;
  // 1024 blocks = 4b * 32 bands * 4 xq * 2 dy-halves (xcd-swizzled)
  corr_kernel<<<dim3(1024), dim3(TPB), 0, stream>>>(in1, in2, out);
}